// Round 7
// baseline (1842.254 us; speedup 1.0000x reference)
//
#include <hip/hip_runtime.h>

// Seq2Seq GRU: B=256, S=128, T=64, I=63, H=1024. Inputs fp32, output fp32.
// All GEMMs: bf16 hi+lo 3-term split emulation (~fp32 accuracy).
// Encoder v12 == R3's proven enc_persist8 (best measured: 1374us) with ONE
//   change: XCD-PAIR GROUP MAPPING. Each mt-group's 64 blocks now live on
//   XCDs {2mt, 2mt+1} (was: spread across all 8). All h exchange for a
//   group stays within 2 L2s -> each h line is MALL-filled into 2 L2s
//   instead of 8; wave w's 8 producers sit on one XCD.
//   old: mt=(bid>>3)&3, jt=(bid&7)*8+(bid>>5)
//   new: mt=(bid&7)>>1, jt=(bid&1)*32+(bid>>3)
//   Counter protocol index-identical (sub-counter (mt, jt>>3), 8 posts;
//   wave w polls (mt,w) == its K-slice's producer octet). G16-safe: all
//   stores/atomics remain system-scope; a wrong XCD-mapping assumption
//   can only cost speed, never correctness.
// R6 lesson: 16-wave blocks cap VGPR at 128 -> register-resident design
//   infeasible; this kernel stays at 512 thr / 8 waves / 128 VGPR.

typedef unsigned short u16;
typedef unsigned int   u32;
typedef __attribute__((ext_vector_type(8))) short s8v;   // 8 x bf16 (4 VGPRs)
typedef __attribute__((ext_vector_type(4))) float f4v;   // MFMA acc
typedef __attribute__((ext_vector_type(4))) int  i4v;    // 16B copy unit
typedef __attribute__((ext_vector_type(4))) unsigned int u4v;

__device__ __forceinline__ float b2f(u16 u) {
    return __uint_as_float(((u32)u) << 16);
}
__device__ __forceinline__ u16 f2b(float f) {   // round-to-nearest-even
    u32 x = __float_as_uint(f);
    u32 r = x + 0x7fffu + ((x >> 16) & 1u);
    return (u16)(r >> 16);
}
__device__ __forceinline__ float sigf(float x) {
    return 1.0f / (1.0f + __expf(-x));
}
__device__ __forceinline__ f4v mfma16(s8v a, s8v b, f4v c) {
    return __builtin_amdgcn_mfma_f32_16x16x32_bf16(a, b, c, 0, 0, 0);
}
// 8 packed u32 (hh|ll<<16) -> hi-plane s8v + lo-plane s8v
__device__ __forceinline__ void unpack8(u4v w0, u4v w1, s8v& hi, s8v& lo) {
    u32 c0 = w0[0], c1 = w0[1], c2 = w0[2], c3 = w0[3];
    u32 c4 = w1[0], c5 = w1[1], c6 = w1[2], c7 = w1[3];
    union { u32 u[4]; s8v v; } H, L;
    H.u[0] = (c0 & 0xffffu) | (c1 << 16);
    H.u[1] = (c2 & 0xffffu) | (c3 << 16);
    H.u[2] = (c4 & 0xffffu) | (c5 << 16);
    H.u[3] = (c6 & 0xffffu) | (c7 << 16);
    L.u[0] = (c0 >> 16) | (c1 & 0xffff0000u);
    L.u[1] = (c2 >> 16) | (c3 & 0xffff0000u);
    L.u[2] = (c4 >> 16) | (c5 & 0xffff0000u);
    L.u[3] = (c6 >> 16) | (c7 & 0xffff0000u);
    hi = H.v; lo = L.v;
}

// ---------------------------------------------------------------------------
__global__ void zero_ws(i4v* __restrict__ p, int n) {
    int i = blockIdx.x * blockDim.x + threadIdx.x;
    if (i < n) { i4v z = {0, 0, 0, 0}; p[i] = z; }
}

// Wih (3072 x 63 fp32) -> padded (3072 x 64) hi+lo, col 63 = 0
__global__ void conv_wih_split_pad(const float* __restrict__ s,
                                   u16* __restrict__ hi, u16* __restrict__ lo) {
    int idx = blockIdx.x * blockDim.x + threadIdx.x;
    int row = idx >> 6, col = idx & 63;
    float v = (col < 63) ? s[(size_t)row * 63 + col] : 0.f;
    u16 h = f2b(v);
    hi[idx] = h;
    lo[idx] = f2b(v - b2f(h));
}

// proj_W (63 x 1024 fp32) -> padded (64 x 1024) hi+lo, row 63 = 0
__global__ void conv_pw_split_pad(const float* __restrict__ s,
                                  u16* __restrict__ hi, u16* __restrict__ lo) {
    int idx = blockIdx.x * blockDim.x + threadIdx.x;
    float v = (idx < 63 * 1024) ? s[idx] : 0.f;
    u16 h = f2b(v);
    hi[idx] = h;
    lo[idx] = f2b(v - b2f(h));
}

// ---------------------------------------------------------------------------
// Persistent encoder v12 (R3 body, XCD-pair mapping).
__global__ __launch_bounds__(512, 1) void enc_persist12(
    const float* __restrict__ Whh,                 // fp32 3072 x 1024
    const u16* __restrict__ WihH, const u16* __restrict__ WihL,
    const float* __restrict__ bih, const float* __restrict__ bhh,
    const float* __restrict__ xenc,
    u32* __restrict__ hbuf,                        // 129 x (256x1024) packed
    int* __restrict__ ep)                          // 32 sub-counters x 64B
{
    __shared__ f4v red[8][4][3][64];   // 98.3 KB: per-wave k-slice partials
    __shared__ u16 WisH[48 * 72];      // Wih slice (persistent)
    __shared__ u16 WisL[48 * 72];

    // one-time: drop stale lines from a previous graph replay
    __builtin_amdgcn_fence(__ATOMIC_ACQUIRE, "agent");

    const int tid  = threadIdx.x;
    const int lane = tid & 63;
    const int wave = tid >> 6;          // 0..7 : k-slice owner, k0 = wave*128
    const int lrow = lane & 15;
    const int lk8  = lane >> 4;
    // XCD-PAIR mapping: group mt lives on XCDs {2mt, 2mt+1}.
    const int bid = blockIdx.x;
    const int xcd = bid & 7;
    const int mt  = xcd >> 1;                       // 0..3
    const int jt  = (xcd & 1) * 32 + (bid >> 3);    // 0..63
    const int m0 = mt * 64;
    const int j0 = jt * 16;

    // sub-counter (mt, octet): octet o = jt>>3; its 8 blocks post each step.
    int* subCtr  = ep + (mt * 8 + (jt >> 3)) * 16;
    // wave w's producers are exactly octet w -> ONE counter.
    int* waveCtr = ep + (mt * 8 + wave) * 16;

    // ---- one-time: Wih slice into LDS
    if (tid < 192) {
        int wr = tid >> 2, qq = tid & 3;
        int grow = (wr >> 4) * 1024 + j0 + (wr & 15);
        const u16* wpH = WihH + (size_t)grow * 64 + qq * 16;
        const u16* wpL = WihL + (size_t)grow * 64 + qq * 16;
        *(i4v*)&WisH[wr * 72 + qq * 16]     = *(const i4v*)wpH;
        *(i4v*)&WisH[wr * 72 + qq * 16 + 8] = *(const i4v*)(wpH + 8);
        *(i4v*)&WisL[wr * 72 + qq * 16]     = *(const i4v*)wpL;
        *(i4v*)&WisL[wr * 72 + qq * 16 + 8] = *(const i4v*)(wpL + 8);
    }

    // ---- one-time: this wave's Whh K-slice fp32 -> bf16 hi+lo in registers
    s8v bHf[3][4], bLf[3][4];
    const int k0 = wave * 128;
    #pragma unroll
    for (int gg = 0; gg < 3; ++gg)
        #pragma unroll
        for (int ks = 0; ks < 4; ++ks) {
            const float* p = Whh + (size_t)(gg * 1024 + j0 + lrow) * 1024 +
                             k0 + ks * 32 + lk8 * 8;
            f4v a = *(const f4v*)p;
            f4v b = *(const f4v*)(p + 4);
            union { u16 a[8]; s8v v; } H, L;
            #pragma unroll
            for (int j = 0; j < 8; ++j) {
                float v = (j < 4) ? a[j] : b[j - 4];
                u16 hh = f2b(v);
                H.a[j] = hh;
                L.a[j] = f2b(v - b2f(hh));
            }
            bHf[gg][ks] = H.v;
            bLf[gg][ks] = L.v;
        }

    const int jcol = j0 + lrow;
    const float bhr = bhh[jcol], bhz = bhh[1024 + jcol], bhn = bhh[2048 + jcol];
    const float bir = bih[jcol], biz = bih[1024 + jcol], bin = bih[2048 + jcol];

    // A-load element offsets per m-tile (u32 elements)
    size_t aoff[4];
    #pragma unroll
    for (int mtile = 0; mtile < 4; ++mtile)
        aoff[mtile] = (size_t)(m0 + mtile * 16 + lrow) * 1024 + k0 + lk8 * 8;

    // gi / epilogue waves: wave v (0..3) owns m-tile v
    const float* xrow = xenc + (size_t)(m0 + (wave & 3) * 16 + lrow) * 8064;
    float hprev[4] = {0.f, 0.f, 0.f, 0.f};

    float xf[16];
    if (wave < 4) {
        #pragma unroll
        for (int ks = 0; ks < 2; ++ks)
            #pragma unroll
            for (int j = 0; j < 8; ++j) {
                int col = ks * 32 + lk8 * 8 + j;
                xf[ks * 8 + j] = (col < 63) ? xrow[col] : 0.f;
            }
    }

    __syncthreads();   // Wis ready

    for (int s = 0; s < 128; ++s) {
        const u32* hin = hbuf + (size_t)s * 262144;        // read buf[s]
        u32* hout      = hbuf + (size_t)(s + 1) * 262144;  // write buf[s+1]

        // ---- gi (waves 0-3): h-independent -> compute in the wait shadow
        f4v gi_r = {0.f, 0.f, 0.f, 0.f};
        f4v gi_z = {0.f, 0.f, 0.f, 0.f};
        f4v gi_n = {0.f, 0.f, 0.f, 0.f};
        if (wave < 4) {
            #pragma unroll
            for (int ks = 0; ks < 2; ++ks) {
                union { u16 a[8]; s8v v; } xh, xl;
                #pragma unroll
                for (int j = 0; j < 8; ++j) {
                    float v = xf[ks * 8 + j];
                    u16 hh = f2b(v);
                    xh.a[j] = hh;
                    xl.a[j] = f2b(v - b2f(hh));
                }
                int ao = ks * 32 + lk8 * 8;
                s8v brh = *(const s8v*)&WisH[(lrow) * 72 + ao];
                s8v brl = *(const s8v*)&WisL[(lrow) * 72 + ao];
                s8v bzh = *(const s8v*)&WisH[(16 + lrow) * 72 + ao];
                s8v bzl = *(const s8v*)&WisL[(16 + lrow) * 72 + ao];
                s8v bnh = *(const s8v*)&WisH[(32 + lrow) * 72 + ao];
                s8v bnl = *(const s8v*)&WisL[(32 + lrow) * 72 + ao];
                gi_r = mfma16(xh.v, brh, gi_r);
                gi_z = mfma16(xh.v, bzh, gi_z);
                gi_n = mfma16(xh.v, bnh, gi_n);
                gi_r = mfma16(xh.v, brl, gi_r);
                gi_z = mfma16(xh.v, bzl, gi_z);
                gi_n = mfma16(xh.v, bnl, gi_n);
                gi_r = mfma16(xl.v, brh, gi_r);
                gi_z = mfma16(xl.v, bzh, gi_z);
                gi_n = mfma16(xl.v, bnh, gi_n);
            }
        }

        // ---- per-wave wait: only THIS wave's 8 producers (one counter).
        if (s) {
            const int tgt = s * 8;
            while (__hip_atomic_load(waveCtr, __ATOMIC_RELAXED,
                                     __HIP_MEMORY_SCOPE_SYSTEM) < tgt)
                __builtin_amdgcn_s_sleep(1);
        }

        // ---- K loop: 4 m-tiles x 4 ks, B in regs, packed-A unpack
        f4v accr[4], accz[4], acchn[4];
        #pragma unroll
        for (int m = 0; m < 4; ++m) {
            accr[m]  = f4v{0.f, 0.f, 0.f, 0.f};
            accz[m]  = f4v{0.f, 0.f, 0.f, 0.f};
            acchn[m] = f4v{0.f, 0.f, 0.f, 0.f};
        }
        #pragma unroll
        for (int mtile = 0; mtile < 4; ++mtile) {
            #pragma unroll
            for (int ks = 0; ks < 4; ++ks) {
                const u32* p = hin + aoff[mtile] + ks * 32;
                u4v w0 = *(const u4v*)p;
                u4v w1 = *(const u4v*)(p + 4);
                s8v ahi, alo;
                unpack8(w0, w1, ahi, alo);
                accr[mtile]  = mfma16(ahi, bHf[0][ks], accr[mtile]);
                accz[mtile]  = mfma16(ahi, bHf[1][ks], accz[mtile]);
                acchn[mtile] = mfma16(ahi, bHf[2][ks], acchn[mtile]);
                accr[mtile]  = mfma16(ahi, bLf[0][ks], accr[mtile]);
                accz[mtile]  = mfma16(ahi, bLf[1][ks], accz[mtile]);
                acchn[mtile] = mfma16(ahi, bLf[2][ks], acchn[mtile]);
                accr[mtile]  = mfma16(alo, bHf[0][ks], accr[mtile]);
                accz[mtile]  = mfma16(alo, bHf[1][ks], accz[mtile]);
                acchn[mtile] = mfma16(alo, bHf[2][ks], acchn[mtile]);
            }
        }

        // ---- write k-slice partials
        #pragma unroll
        for (int m = 0; m < 4; ++m) {
            red[wave][m][0][lane] = accr[m];
            red[wave][m][1][lane] = accz[m];
            red[wave][m][2][lane] = acchn[m];
        }
        __syncthreads();

        // ---- epilogue (waves 0-3): 8-way reduce, gates, packed h store
        if (wave < 4) {
            f4v sr = {0.f, 0.f, 0.f, 0.f};
            f4v sz = {0.f, 0.f, 0.f, 0.f};
            f4v sh = {0.f, 0.f, 0.f, 0.f};
            #pragma unroll
            for (int w = 0; w < 8; ++w) {
                sr += red[w][wave][0][lane];
                sz += red[w][wave][1][lane];
                sh += red[w][wave][2][lane];
            }
            #pragma unroll
            for (int reg = 0; reg < 4; ++reg) {
                int brow = m0 + wave * 16 + lk8 * 4 + reg;
                float rr = sigf(sr[reg] + gi_r[reg] + bir + bhr);
                float zz = sigf(sz[reg] + gi_z[reg] + biz + bhz);
                float nn = tanhf(gi_n[reg] + bin + rr * (sh[reg] + bhn));
                float h = (1.f - zz) * nn + zz * hprev[reg];
                u16 hh = f2b(h);
                u16 ll = f2b(h - b2f(hh));
                hprev[reg] = b2f(hh) + b2f(ll);
                u32 pk = (u32)hh | ((u32)ll << 16);
                // write-through (sc0 sc1): visible once vmcnt drains at the
                // barrier below -> no wbl2 needed.
                __hip_atomic_store(&hout[(size_t)brow * 1024 + jcol], pk,
                                   __ATOMIC_RELAXED, __HIP_MEMORY_SCOPE_SYSTEM);
            }
        }

        __syncthreads();   // drains h stores (vmcnt 0 per wave)
        if (tid == 0)
            __hip_atomic_fetch_add(subCtr, 1, __ATOMIC_RELAXED,
                                   __HIP_MEMORY_SCOPE_SYSTEM);
        // prefetch next step's x (immutable input)
        if (wave < 4) {
            int sn = (s < 127) ? s + 1 : 127;
            const float* xr = xrow + sn * 63;
            #pragma unroll
            for (int ks = 0; ks < 2; ++ks)
                #pragma unroll
                for (int j = 0; j < 8; ++j) {
                    int col = ks * 32 + lk8 * 8 + j;
                    xf[ks * 8 + j] = (col < 63) ? xr[col] : 0.f;
                }
        }
    }
}

// ---------------------------------------------------------------------------
// gh_dec = enc_h @ dec_Whh^T + dec_bhh (fp32 out). dWhh split on the fly.
__global__ __launch_bounds__(256, 1) void gru_gemm1(
    const float* __restrict__ Whh,                 // fp32 3072 x 1024
    const float* __restrict__ bhh,
    const u32* __restrict__ hin,                   // packed hh|ll<<16
    float* __restrict__ gh_out)
{
    __shared__ u16 WbH[48 * 264];
    __shared__ u16 WbL[48 * 264];

    const int tid  = threadIdx.x;
    const int lane = tid & 63;
    const int wave = tid >> 6;
    const int lrow = lane & 15;
    const int lk8  = lane >> 4;
    const int mt = blockIdx.x & 3;
    const int jt = blockIdx.x >> 2;
    const int m0 = mt * 64;
    const int j0 = jt * 16;

    f4v acc_r  = {0.f, 0.f, 0.f, 0.f};
    f4v acc_z  = {0.f, 0.f, 0.f, 0.f};
    f4v acc_hn = {0.f, 0.f, 0.f, 0.f};

    f4v stgA[6], stgB[6];
    #pragma unroll
    for (int i = 0; i < 6; ++i) {
        int c16 = i * 256 + tid;
        int row = c16 >> 5, p16 = c16 & 31;
        int grow = (row >> 4) * 1024 + j0 + (row & 15);
        const float* p = Whh + (size_t)grow * 1024 + p16 * 8;
        stgA[i] = *(const f4v*)p;
        stgB[i] = *(const f4v*)(p + 4);
    }
    #pragma unroll
    for (int i = 0; i < 6; ++i) {
        int c16 = i * 256 + tid;
        int row = c16 >> 5, p16 = c16 & 31;
        union { u16 a[8]; i4v v; } H, L;
        #pragma unroll
        for (int j = 0; j < 8; ++j) {
            float v = (j < 4) ? stgA[i][j] : stgB[i][j - 4];
            u16 hh = f2b(v);
            H.a[j] = hh;
            L.a[j] = f2b(v - b2f(hh));
        }
        *(i4v*)&WbH[row * 264 + p16 * 8] = H.v;
        *(i4v*)&WbL[row * 264 + p16 * 8] = L.v;
    }
    __syncthreads();

    const size_t arow = (size_t)(m0 + wave * 16 + lrow) * 1024 + lk8 * 8;
    const u32* hp = hin + arow;

    for (int c = 0; c < 4; ++c) {
        if (c < 3) {
            #pragma unroll
            for (int i = 0; i < 6; ++i) {
                int c16 = i * 256 + tid;
                int row = c16 >> 5, p16 = c16 & 31;
                int grow = (row >> 4) * 1024 + j0 + (row & 15);
                const float* p = Whh + (size_t)grow * 1024 + (c + 1) * 256 + p16 * 8;
                stgA[i] = *(const f4v*)p;
                stgB[i] = *(const f4v*)(p + 4);
            }
        }
        #pragma unroll
        for (int ks = 0; ks < 8; ++ks) {
            int kk = c * 256 + ks * 32;
            int bo = ks * 32 + lk8 * 8;
            u4v w0 = *(const u4v*)(hp + kk);
            u4v w1 = *(const u4v*)(hp + kk + 4);
            s8v ahi, alo;
            unpack8(w0, w1, ahi, alo);
            s8v brh = *(const s8v*)&WbH[(lrow) * 264 + bo];
            s8v brl = *(const s8v*)&WbL[(lrow) * 264 + bo];
            s8v bzh = *(const s8v*)&WbH[(16 + lrow) * 264 + bo];
            s8v bzl = *(const s8v*)&WbL[(16 + lrow) * 264 + bo];
            s8v bnh = *(const s8v*)&WbH[(32 + lrow) * 264 + bo];
            s8v bnl = *(const s8v*)&WbL[(32 + lrow) * 264 + bo];
            acc_r  = mfma16(ahi, brh, acc_r);
            acc_z  = mfma16(ahi, bzh, acc_z);
            acc_hn = mfma16(ahi, bnh, acc_hn);
            acc_r  = mfma16(ahi, brl, acc_r);
            acc_z  = mfma16(ahi, bzl, acc_z);
            acc_hn = mfma16(ahi, bnl, acc_hn);
            acc_r  = mfma16(alo, brh, acc_r);
            acc_z  = mfma16(alo, bzh, acc_z);
            acc_hn = mfma16(alo, bnh, acc_hn);
        }
        __syncthreads();
        if (c < 3) {
            #pragma unroll
            for (int i = 0; i < 6; ++i) {
                int c16 = i * 256 + tid;
                int row = c16 >> 5, p16 = c16 & 31;
                union { u16 a[8]; i4v v; } H, L;
                #pragma unroll
                for (int j = 0; j < 8; ++j) {
                    float v = (j < 4) ? stgA[i][j] : stgB[i][j - 4];
                    u16 hh = f2b(v);
                    H.a[j] = hh;
                    L.a[j] = f2b(v - b2f(hh));
                }
                *(i4v*)&WbH[row * 264 + p16 * 8] = H.v;
                *(i4v*)&WbL[row * 264 + p16 * 8] = L.v;
            }
            __syncthreads();
        }
    }

    const int jcol = j0 + lrow;
    const float bhr = bhh[jcol];
    const float bhz = bhh[1024 + jcol];
    const float bhn = bhh[2048 + jcol];
    #pragma unroll
    for (int reg = 0; reg < 4; ++reg) {
        int brow = m0 + wave * 16 + lk8 * 4 + reg;
        gh_out[(size_t)brow * 3072 + jcol]        = acc_r[reg] + bhr;
        gh_out[(size_t)brow * 3072 + 1024 + jcol] = acc_z[reg] + bhz;
        gh_out[(size_t)brow * 3072 + 2048 + jcol] = acc_hn[reg] + bhn;
    }
}

// ---------------------------------------------------------------------------
// Fused decoder (enc_h packed u32)
__global__ __launch_bounds__(256, 1) void dec_fused(
    const u16* __restrict__ WihH, const u16* __restrict__ WihL,
    const float* __restrict__ bih,
    const float* __restrict__ xdec,
    const u32* __restrict__ e32,
    const float* __restrict__ gh,
    const u16* __restrict__ pWH, const u16* __restrict__ pWL,
    const float* __restrict__ pb,
    float* __restrict__ out)
{
    __shared__ u16 XdH[64 * 72];
    __shared__ u16 XdL[64 * 72];
    __shared__ u16 WiH_[192 * 72];
    __shared__ u16 WiL_[192 * 72];
    __shared__ u16 nsH[64 * 72];
    __shared__ u16 nsL[64 * 72];

    const int tid  = threadIdx.x;
    const int lane = tid & 63;
    const int wave = tid >> 6;
    const int lrow = lane & 15;
    const int lk8  = lane >> 4;
    const int b    = blockIdx.x;

    {
        int row = tid >> 2, q = tid & 3;
        const float* xr = xdec + (size_t)(b * 64 + row) * 63;
        #pragma unroll
        for (int ii = 0; ii < 16; ++ii) {
            int col = q * 16 + ii;
            float v = (col < 63) ? xr[col] : 0.f;
            u16 hh = f2b(v);
            XdH[row * 72 + col] = hh;
            XdL[row * 72 + col] = f2b(v - b2f(hh));
        }
    }

    f4v oacc[4];
    #pragma unroll
    for (int f = 0; f < 4; ++f) oacc[f] = f4v{0.f, 0.f, 0.f, 0.f};

    for (int j0 = 0; j0 < 1024; j0 += 64) {
        #pragma unroll
        for (int k = 0; k < 3; ++k) {
            int c = tid + k * 256;
            int r = c >> 2, qq = c & 3;
            int grow = (r >> 6) * 1024 + j0 + (r & 63);
            const u16* srcH = WihH + (size_t)grow * 64 + qq * 16;
            const u16* srcL = WihL + (size_t)grow * 64 + qq * 16;
            *(i4v*)&WiH_[r * 72 + qq * 16]     = *(const i4v*)srcH;
            *(i4v*)&WiH_[r * 72 + qq * 16 + 8] = *(const i4v*)(srcH + 8);
            *(i4v*)&WiL_[r * 72 + qq * 16]     = *(const i4v*)srcL;
            *(i4v*)&WiL_[r * 72 + qq * 16 + 8] = *(const i4v*)(srcL + 8);
        }
        __syncthreads();

        f4v ar[4], az[4], an[4];
        #pragma unroll
        for (int jf = 0; jf < 4; ++jf) {
            ar[jf] = f4v{0.f, 0.f, 0.f, 0.f};
            az[jf] = f4v{0.f, 0.f, 0.f, 0.f};
            an[jf] = f4v{0.f, 0.f, 0.f, 0.f};
        }
        #pragma unroll
        for (int ks = 0; ks < 2; ++ks) {
            int ao = ks * 32 + lk8 * 8;
            s8v ah = *(const s8v*)&XdH[(wave * 16 + lrow) * 72 + ao];
            s8v al = *(const s8v*)&XdL[(wave * 16 + lrow) * 72 + ao];
            #pragma unroll
            for (int jf = 0; jf < 4; ++jf) {
                s8v brh = *(const s8v*)&WiH_[(jf * 16 + lrow) * 72 + ao];
                s8v brl = *(const s8v*)&WiL_[(jf * 16 + lrow) * 72 + ao];
                s8v bzh = *(const s8v*)&WiH_[(64 + jf * 16 + lrow) * 72 + ao];
                s8v bzl = *(const s8v*)&WiL_[(64 + jf * 16 + lrow) * 72 + ao];
                s8v bnh = *(const s8v*)&WiH_[(128 + jf * 16 + lrow) * 72 + ao];
                s8v bnl = *(const s8v*)&WiL_[(128 + jf * 16 + lrow) * 72 + ao];
                ar[jf] = mfma16(ah, brh, ar[jf]);
                az[jf] = mfma16(ah, bzh, az[jf]);
                an[jf] = mfma16(ah, bnh, an[jf]);
                ar[jf] = mfma16(ah, brl, ar[jf]);
                az[jf] = mfma16(ah, bzl, az[jf]);
                an[jf] = mfma16(ah, bnl, an[jf]);
                ar[jf] = mfma16(al, brh, ar[jf]);
                az[jf] = mfma16(al, bzh, az[jf]);
                an[jf] = mfma16(al, bnh, an[jf]);
            }
        }

        #pragma unroll
        for (int jf = 0; jf < 4; ++jf) {
            int j = j0 + jf * 16 + lrow;
            float ghr = gh[(size_t)b * 3072 + j];
            float ghz = gh[(size_t)b * 3072 + 1024 + j];
            float ghn = gh[(size_t)b * 3072 + 2048 + j];
            float bir = bih[j];
            float biz = bih[1024 + j];
            float bin = bih[2048 + j];
            u32 pk = e32[(size_t)b * 1024 + j];
            float he = b2f((u16)(pk & 0xffffu)) + b2f((u16)(pk >> 16));
            #pragma unroll
            for (int reg = 0; reg < 4; ++reg) {
                float r  = sigf(ar[jf][reg] + bir + ghr);
                float z  = sigf(az[jf][reg] + biz + ghz);
                float nn = tanhf(an[jf][reg] + bin + r * ghn);
                float v  = (1.f - z) * nn + z * he;
                u16 hh = f2b(v);
                int lo_i = (wave * 16 + lk8 * 4 + reg) * 72 + jf * 16 + lrow;
                nsH[lo_i] = hh;
                nsL[lo_i] = f2b(v - b2f(hh));
            }
        }
        __syncthreads();

        #pragma unroll
        for (int ks = 0; ks < 2; ++ks) {
            int ao = ks * 32 + lk8 * 8;
            s8v ah = *(const s8v*)&nsH[(wave * 16 + lrow) * 72 + ao];
            s8v al = *(const s8v*)&nsL[(wave * 16 + lrow) * 72 + ao];
            #pragma unroll
            for (int f = 0; f < 4; ++f) {
                size_t bo = (size_t)(f * 16 + lrow) * 1024 + j0 + ks * 32 + lk8 * 8;
                s8v bh = *(const s8v*)(pWH + bo);
                s8v bl = *(const s8v*)(pWL + bo);
                oacc[f] = mfma16(ah, bh, oacc[f]);
                oacc[f] = mfma16(ah, bl, oacc[f]);
                oacc[f] = mfma16(al, bh, oacc[f]);
            }
        }
        __syncthreads();
    }

    #pragma unroll
    for (int f = 0; f < 4; ++f) {
        int o = f * 16 + lrow;
        if (o < 63) {
            float pbv = pb[o];
            #pragma unroll
            for (int reg = 0; reg < 4; ++reg) {
                int t = wave * 16 + lk8 * 4 + reg;
                out[((size_t)(b * 64 + t)) * 63 + o] = oacc[f][reg] + pbv;
            }
        }
    }
}

// ---------------------------------------------------------------------------
extern "C" void kernel_launch(void* const* d_in, const int* in_sizes, int n_in,
                              void* d_out, int out_size, void* d_ws, size_t ws_size,
                              hipStream_t stream)
{
    const float* enc_x = (const float*)d_in[0];
    const float* dec_x = (const float*)d_in[1];
    const float* eWih  = (const float*)d_in[2];
    const float* eWhh  = (const float*)d_in[3];
    const float* ebih  = (const float*)d_in[4];
    const float* ebhh  = (const float*)d_in[5];
    const float* dWih  = (const float*)d_in[6];
    const float* dWhh  = (const float*)d_in[7];
    const float* dbih  = (const float*)d_in[8];
    const float* dbhh  = (const float*)d_in[9];
    const float* pW    = (const float*)d_in[10];
    const float* pb    = (const float*)d_in[11];

    char* ws = (char*)d_ws;

    // layout: 129MB hbuf(packed) + 16KB ep + 3MB ghd + 4x384KB Wih + 2x128KB pW
    u32*   hbuf  = (u32*)(ws);                     // 129 x 1MB rotating packed h
    int*   ep    = (int*)(ws + 135266304);         // 16 KB sub-counters
    float* ghd   = (float*)(ws + 135282688);       // 3 MB
    u16*   eWihH = (u16*)(ws + 138428416);         // 384 KB each
    u16*   eWihL = (u16*)(ws + 138821632);
    u16*   dWihH = (u16*)(ws + 139214848);
    u16*   dWihL = (u16*)(ws + 139608064);
    u16*   pWH   = (u16*)(ws + 140001280);         // 128 KB each
    u16*   pWL   = (u16*)(ws + 140132352);

    // small one-time conversions (Wih pad + proj pad); Whh splits are in-kernel
    conv_wih_split_pad<<<dim3(768), dim3(256), 0, stream>>>(eWih, eWihH, eWihL);
    conv_wih_split_pad<<<dim3(768), dim3(256), 0, stream>>>(dWih, dWihH, dWihL);
    conv_pw_split_pad<<<dim3(256), dim3(256), 0, stream>>>(pW, pWH, pWL);

    // zero buf[0] (1 MB packed) + sub-counters (16 KB)
    zero_ws<<<dim3(256), dim3(256), 0, stream>>>((i4v*)hbuf, 65536);
    zero_ws<<<dim3(4), dim3(256), 0, stream>>>((i4v*)ep, 1024);

    // persistent encoder: all 128 steps, one launch
    enc_persist12<<<dim3(256), dim3(512), 0, stream>>>(
        eWhh, eWihH, eWihL, ebih, ebhh, enc_x, hbuf, ep);

    u32* Hfin = hbuf + (size_t)128 * 262144;       // buf[128]

    // gh_dec = enc_h @ dec_Whh^T + dec_bhh (dWhh split on the fly)
    gru_gemm1<<<dim3(256), dim3(256), 0, stream>>>(dWhh, dbhh, Hfin, ghd);

    // fused decoder gates + projection -> fp32 out
    dec_fused<<<dim3(256), dim3(256), 0, stream>>>(
        dWihH, dWihL, dbih, dec_x, Hfin, ghd, pWH, pWL, pb, (float*)d_out);
}

// Round 8
// 1555.830 us; speedup vs baseline: 1.1841x; 1.1841x over previous
//
#include <hip/hip_runtime.h>

// Seq2Seq GRU: B=256, S=128, T=64, I=63, H=1024. Inputs fp32, output fp32.
// All GEMMs: bf16 hi+lo 3-term split emulation (~fp32 accuracy).
// Encoder v13 = R3's proven enc_persist8 (best measured: 1374us enc / 1520
//   total; R4/R5/R7 structural variants all regressed) + two safe shavings:
//   1) EARLY PER-EPILOGUE-WAVE POSTS: each epilogue wave drains its OWN
//      stores (s_waitcnt vmcnt(0)) and fetch_adds immediately -- the flag
//      no longer waits for the trailing block-wide barrier. Counter target
//      8s -> 32s (8 blocks x 4 epilogue waves per octet). red[] stays
//      protected by the unchanged two barriers; consumer correctness:
//      32(s+1) posts  <=>  all producer h-stores drained (R4-proven
//      pattern). Skew<=1 induction unchanged.
//   2) FUSED PROLOGUE: one 2049-block kernel replaces 5 serial launches
//      (2x conv_wih + conv_pw + zero hbuf[0] + zero counters).
// Mapping/protocol/packing identical to R3: all-XCD spread (R7 proved
// locality-concentration hurts), packed u32 h, per-wave decoupled waits.

typedef unsigned short u16;
typedef unsigned int   u32;
typedef __attribute__((ext_vector_type(8))) short s8v;   // 8 x bf16 (4 VGPRs)
typedef __attribute__((ext_vector_type(4))) float f4v;   // MFMA acc
typedef __attribute__((ext_vector_type(4))) int  i4v;    // 16B copy unit
typedef __attribute__((ext_vector_type(4))) unsigned int u4v;

__device__ __forceinline__ float b2f(u16 u) {
    return __uint_as_float(((u32)u) << 16);
}
__device__ __forceinline__ u16 f2b(float f) {   // round-to-nearest-even
    u32 x = __float_as_uint(f);
    u32 r = x + 0x7fffu + ((x >> 16) & 1u);
    return (u16)(r >> 16);
}
__device__ __forceinline__ float sigf(float x) {
    return 1.0f / (1.0f + __expf(-x));
}
__device__ __forceinline__ f4v mfma16(s8v a, s8v b, f4v c) {
    return __builtin_amdgcn_mfma_f32_16x16x32_bf16(a, b, c, 0, 0, 0);
}
// 8 packed u32 (hh|ll<<16) -> hi-plane s8v + lo-plane s8v
__device__ __forceinline__ void unpack8(u4v w0, u4v w1, s8v& hi, s8v& lo) {
    u32 c0 = w0[0], c1 = w0[1], c2 = w0[2], c3 = w0[3];
    u32 c4 = w1[0], c5 = w1[1], c6 = w1[2], c7 = w1[3];
    union { u32 u[4]; s8v v; } H, L;
    H.u[0] = (c0 & 0xffffu) | (c1 << 16);
    H.u[1] = (c2 & 0xffffu) | (c3 << 16);
    H.u[2] = (c4 & 0xffffu) | (c5 << 16);
    H.u[3] = (c6 & 0xffffu) | (c7 << 16);
    L.u[0] = (c0 >> 16) | (c1 & 0xffff0000u);
    L.u[1] = (c2 >> 16) | (c3 & 0xffff0000u);
    L.u[2] = (c4 >> 16) | (c5 & 0xffff0000u);
    L.u[3] = (c6 >> 16) | (c7 & 0xffff0000u);
    hi = H.v; lo = L.v;
}

// ---------------------------------------------------------------------------
// Fused prologue: blocks [0,768) eWih pad-split, [768,1536) dWih pad-split,
// [1536,1792) pW pad-split, [1792,2048) zero hbuf[0], [2048] zero counters.
__global__ __launch_bounds__(256) void prologue(
    const float* __restrict__ eWih, const float* __restrict__ dWih,
    const float* __restrict__ pW,
    u16* __restrict__ eWihH, u16* __restrict__ eWihL,
    u16* __restrict__ dWihH, u16* __restrict__ dWihL,
    u16* __restrict__ pWH, u16* __restrict__ pWL,
    i4v* __restrict__ hbuf0, i4v* __restrict__ ep)
{
    const int b = blockIdx.x;
    const int tid = threadIdx.x;
    if (b < 1536) {
        // Wih (3072 x 63 fp32) -> padded (3072 x 64) hi+lo, col 63 = 0
        const float* src = (b < 768) ? eWih : dWih;
        u16* hi = (b < 768) ? eWihH : dWihH;
        u16* lo = (b < 768) ? eWihL : dWihL;
        int idx = ((b < 768) ? b : b - 768) * 256 + tid;
        int row = idx >> 6, col = idx & 63;
        float v = (col < 63) ? src[(size_t)row * 63 + col] : 0.f;
        u16 h = f2b(v);
        hi[idx] = h;
        lo[idx] = f2b(v - b2f(h));
    } else if (b < 1792) {
        // proj_W (63 x 1024 fp32) -> padded (64 x 1024) hi+lo, row 63 = 0
        int idx = (b - 1536) * 256 + tid;
        float v = (idx < 63 * 1024) ? pW[idx] : 0.f;
        u16 h = f2b(v);
        pWH[idx] = h;
        pWL[idx] = f2b(v - b2f(h));
    } else if (b < 2048) {
        // zero hbuf[0]: 65536 i4v
        i4v z = {0, 0, 0, 0};
        hbuf0[(b - 1792) * 256 + tid] = z;
    } else {
        // zero counters: 1024 i4v
        i4v z = {0, 0, 0, 0};
        for (int i = tid; i < 1024; i += 256) ep[i] = z;
    }
}

// ---------------------------------------------------------------------------
// Persistent encoder v13 (R3 body + early per-epilogue-wave posts).
__global__ __launch_bounds__(512, 1) void enc_persist13(
    const float* __restrict__ Whh,                 // fp32 3072 x 1024
    const u16* __restrict__ WihH, const u16* __restrict__ WihL,
    const float* __restrict__ bih, const float* __restrict__ bhh,
    const float* __restrict__ xenc,
    u32* __restrict__ hbuf,                        // 129 x (256x1024) packed
    int* __restrict__ ep)                          // 32 sub-counters x 64B
{
    __shared__ f4v red[8][4][3][64];   // 98.3 KB: per-wave k-slice partials
    __shared__ u16 WisH[48 * 72];      // Wih slice (persistent)
    __shared__ u16 WisL[48 * 72];

    // one-time: drop stale lines from a previous graph replay
    __builtin_amdgcn_fence(__ATOMIC_ACQUIRE, "agent");

    const int tid  = threadIdx.x;
    const int lane = tid & 63;
    const int wave = tid >> 6;          // 0..7 : k-slice owner, k0 = wave*128
    const int lrow = lane & 15;
    const int lk8  = lane >> 4;
    // XCD-aware swizzle (R3-proven): bid&7 = XCD; XCD owns a 128-col j-range.
    const int bid = blockIdx.x;
    const int xcd = bid & 7;
    const int y   = bid >> 3;
    const int mt  = y & 3;
    const int jt  = xcd * 8 + (y >> 2);
    const int m0 = mt * 64;
    const int j0 = jt * 16;

    // sub-counter (mt, xcd): 8 blocks x 4 epilogue waves post each step.
    int* subCtr  = ep + (mt * 8 + xcd) * 16;
    // wave w's producers (jt' in [8w,8w+8)) all post counter (mt,w).
    int* waveCtr = ep + (mt * 8 + wave) * 16;

    // ---- one-time: Wih slice into LDS
    if (tid < 192) {
        int wr = tid >> 2, qq = tid & 3;
        int grow = (wr >> 4) * 1024 + j0 + (wr & 15);
        const u16* wpH = WihH + (size_t)grow * 64 + qq * 16;
        const u16* wpL = WihL + (size_t)grow * 64 + qq * 16;
        *(i4v*)&WisH[wr * 72 + qq * 16]     = *(const i4v*)wpH;
        *(i4v*)&WisH[wr * 72 + qq * 16 + 8] = *(const i4v*)(wpH + 8);
        *(i4v*)&WisL[wr * 72 + qq * 16]     = *(const i4v*)wpL;
        *(i4v*)&WisL[wr * 72 + qq * 16 + 8] = *(const i4v*)(wpL + 8);
    }

    // ---- one-time: this wave's Whh K-slice fp32 -> bf16 hi+lo in registers
    s8v bHf[3][4], bLf[3][4];
    const int k0 = wave * 128;
    #pragma unroll
    for (int gg = 0; gg < 3; ++gg)
        #pragma unroll
        for (int ks = 0; ks < 4; ++ks) {
            const float* p = Whh + (size_t)(gg * 1024 + j0 + lrow) * 1024 +
                             k0 + ks * 32 + lk8 * 8;
            f4v a = *(const f4v*)p;
            f4v b = *(const f4v*)(p + 4);
            union { u16 a[8]; s8v v; } H, L;
            #pragma unroll
            for (int j = 0; j < 8; ++j) {
                float v = (j < 4) ? a[j] : b[j - 4];
                u16 hh = f2b(v);
                H.a[j] = hh;
                L.a[j] = f2b(v - b2f(hh));
            }
            bHf[gg][ks] = H.v;
            bLf[gg][ks] = L.v;
        }

    const int jcol = j0 + lrow;
    const float bhr = bhh[jcol], bhz = bhh[1024 + jcol], bhn = bhh[2048 + jcol];
    const float bir = bih[jcol], biz = bih[1024 + jcol], bin = bih[2048 + jcol];

    // A-load element offsets per m-tile (u32 elements)
    size_t aoff[4];
    #pragma unroll
    for (int mtile = 0; mtile < 4; ++mtile)
        aoff[mtile] = (size_t)(m0 + mtile * 16 + lrow) * 1024 + k0 + lk8 * 8;

    // gi / epilogue waves: wave v (0..3) owns m-tile v
    const float* xrow = xenc + (size_t)(m0 + (wave & 3) * 16 + lrow) * 8064;
    float hprev[4] = {0.f, 0.f, 0.f, 0.f};

    float xf[16];
    if (wave < 4) {
        #pragma unroll
        for (int ks = 0; ks < 2; ++ks)
            #pragma unroll
            for (int j = 0; j < 8; ++j) {
                int col = ks * 32 + lk8 * 8 + j;
                xf[ks * 8 + j] = (col < 63) ? xrow[col] : 0.f;
            }
    }

    __syncthreads();   // Wis ready

    for (int s = 0; s < 128; ++s) {
        const u32* hin = hbuf + (size_t)s * 262144;        // read buf[s]
        u32* hout      = hbuf + (size_t)(s + 1) * 262144;  // write buf[s+1]

        // ---- gi (waves 0-3): h-independent -> compute in the wait shadow
        f4v gi_r = {0.f, 0.f, 0.f, 0.f};
        f4v gi_z = {0.f, 0.f, 0.f, 0.f};
        f4v gi_n = {0.f, 0.f, 0.f, 0.f};
        if (wave < 4) {
            #pragma unroll
            for (int ks = 0; ks < 2; ++ks) {
                union { u16 a[8]; s8v v; } xh, xl;
                #pragma unroll
                for (int j = 0; j < 8; ++j) {
                    float v = xf[ks * 8 + j];
                    u16 hh = f2b(v);
                    xh.a[j] = hh;
                    xl.a[j] = f2b(v - b2f(hh));
                }
                int ao = ks * 32 + lk8 * 8;
                s8v brh = *(const s8v*)&WisH[(lrow) * 72 + ao];
                s8v brl = *(const s8v*)&WisL[(lrow) * 72 + ao];
                s8v bzh = *(const s8v*)&WisH[(16 + lrow) * 72 + ao];
                s8v bzl = *(const s8v*)&WisL[(16 + lrow) * 72 + ao];
                s8v bnh = *(const s8v*)&WisH[(32 + lrow) * 72 + ao];
                s8v bnl = *(const s8v*)&WisL[(32 + lrow) * 72 + ao];
                gi_r = mfma16(xh.v, brh, gi_r);
                gi_z = mfma16(xh.v, bzh, gi_z);
                gi_n = mfma16(xh.v, bnh, gi_n);
                gi_r = mfma16(xh.v, brl, gi_r);
                gi_z = mfma16(xh.v, bzl, gi_z);
                gi_n = mfma16(xh.v, bnl, gi_n);
                gi_r = mfma16(xl.v, brh, gi_r);
                gi_z = mfma16(xl.v, bzh, gi_z);
                gi_n = mfma16(xl.v, bnh, gi_n);
            }
        }

        // ---- per-wave wait: only THIS wave's 8 producers (one counter).
        // Target 32s: 8 blocks x 4 epilogue-wave posts per completed step.
        if (s) {
            const int tgt = s * 32;
            while (__hip_atomic_load(waveCtr, __ATOMIC_RELAXED,
                                     __HIP_MEMORY_SCOPE_SYSTEM) < tgt)
                __builtin_amdgcn_s_sleep(1);
        }

        // ---- K loop: 4 m-tiles x 4 ks, B in regs, packed-A unpack
        f4v accr[4], accz[4], acchn[4];
        #pragma unroll
        for (int m = 0; m < 4; ++m) {
            accr[m]  = f4v{0.f, 0.f, 0.f, 0.f};
            accz[m]  = f4v{0.f, 0.f, 0.f, 0.f};
            acchn[m] = f4v{0.f, 0.f, 0.f, 0.f};
        }
        #pragma unroll
        for (int mtile = 0; mtile < 4; ++mtile) {
            #pragma unroll
            for (int ks = 0; ks < 4; ++ks) {
                const u32* p = hin + aoff[mtile] + ks * 32;
                u4v w0 = *(const u4v*)p;
                u4v w1 = *(const u4v*)(p + 4);
                s8v ahi, alo;
                unpack8(w0, w1, ahi, alo);
                accr[mtile]  = mfma16(ahi, bHf[0][ks], accr[mtile]);
                accz[mtile]  = mfma16(ahi, bHf[1][ks], accz[mtile]);
                acchn[mtile] = mfma16(ahi, bHf[2][ks], acchn[mtile]);
                accr[mtile]  = mfma16(ahi, bLf[0][ks], accr[mtile]);
                accz[mtile]  = mfma16(ahi, bLf[1][ks], accz[mtile]);
                acchn[mtile] = mfma16(ahi, bLf[2][ks], acchn[mtile]);
                accr[mtile]  = mfma16(alo, bHf[0][ks], accr[mtile]);
                accz[mtile]  = mfma16(alo, bHf[1][ks], accz[mtile]);
                acchn[mtile] = mfma16(alo, bHf[2][ks], acchn[mtile]);
            }
        }

        // ---- write k-slice partials
        #pragma unroll
        for (int m = 0; m < 4; ++m) {
            red[wave][m][0][lane] = accr[m];
            red[wave][m][1][lane] = accz[m];
            red[wave][m][2][lane] = acchn[m];
        }
        __syncthreads();   // sync1: red ready

        // ---- epilogue (waves 0-3): reduce, gates, packed h store, EARLY POST
        if (wave < 4) {
            f4v sr = {0.f, 0.f, 0.f, 0.f};
            f4v sz = {0.f, 0.f, 0.f, 0.f};
            f4v sh = {0.f, 0.f, 0.f, 0.f};
            #pragma unroll
            for (int w = 0; w < 8; ++w) {
                sr += red[w][wave][0][lane];
                sz += red[w][wave][1][lane];
                sh += red[w][wave][2][lane];
            }
            #pragma unroll
            for (int reg = 0; reg < 4; ++reg) {
                int brow = m0 + wave * 16 + lk8 * 4 + reg;
                float rr = sigf(sr[reg] + gi_r[reg] + bir + bhr);
                float zz = sigf(sz[reg] + gi_z[reg] + biz + bhz);
                float nn = tanhf(gi_n[reg] + bin + rr * (sh[reg] + bhn));
                float h = (1.f - zz) * nn + zz * hprev[reg];
                u16 hh = f2b(h);
                u16 ll = f2b(h - b2f(hh));
                hprev[reg] = b2f(hh) + b2f(ll);
                u32 pk = (u32)hh | ((u32)ll << 16);
                // write-through (sc0 sc1): globally visible once this wave's
                // vmcnt drains below.
                __hip_atomic_store(&hout[(size_t)brow * 1024 + jcol], pk,
                                   __ATOMIC_RELAXED, __HIP_MEMORY_SCOPE_SYSTEM);
            }
            // early post: drain OWN stores, then signal (R4-proven pattern).
            asm volatile("s_waitcnt vmcnt(0)" ::: "memory");
            if (lane == 0)
                __hip_atomic_fetch_add(subCtr, 1, __ATOMIC_RELAXED,
                                       __HIP_MEMORY_SCOPE_SYSTEM);
        }

        __syncthreads();   // sync2: protects red[] for next iteration
        // prefetch next step's x (immutable input)
        if (wave < 4) {
            int sn = (s < 127) ? s + 1 : 127;
            const float* xr = xrow + sn * 63;
            #pragma unroll
            for (int ks = 0; ks < 2; ++ks)
                #pragma unroll
                for (int j = 0; j < 8; ++j) {
                    int col = ks * 32 + lk8 * 8 + j;
                    xf[ks * 8 + j] = (col < 63) ? xr[col] : 0.f;
                }
        }
    }
}

// ---------------------------------------------------------------------------
// gh_dec = enc_h @ dec_Whh^T + dec_bhh (fp32 out). dWhh split on the fly.
__global__ __launch_bounds__(256, 1) void gru_gemm1(
    const float* __restrict__ Whh,                 // fp32 3072 x 1024
    const float* __restrict__ bhh,
    const u32* __restrict__ hin,                   // packed hh|ll<<16
    float* __restrict__ gh_out)
{
    __shared__ u16 WbH[48 * 264];
    __shared__ u16 WbL[48 * 264];

    const int tid  = threadIdx.x;
    const int lane = tid & 63;
    const int wave = tid >> 6;
    const int lrow = lane & 15;
    const int lk8  = lane >> 4;
    const int mt = blockIdx.x & 3;
    const int jt = blockIdx.x >> 2;
    const int m0 = mt * 64;
    const int j0 = jt * 16;

    f4v acc_r  = {0.f, 0.f, 0.f, 0.f};
    f4v acc_z  = {0.f, 0.f, 0.f, 0.f};
    f4v acc_hn = {0.f, 0.f, 0.f, 0.f};

    f4v stgA[6], stgB[6];
    #pragma unroll
    for (int i = 0; i < 6; ++i) {
        int c16 = i * 256 + tid;
        int row = c16 >> 5, p16 = c16 & 31;
        int grow = (row >> 4) * 1024 + j0 + (row & 15);
        const float* p = Whh + (size_t)grow * 1024 + p16 * 8;
        stgA[i] = *(const f4v*)p;
        stgB[i] = *(const f4v*)(p + 4);
    }
    #pragma unroll
    for (int i = 0; i < 6; ++i) {
        int c16 = i * 256 + tid;
        int row = c16 >> 5, p16 = c16 & 31;
        union { u16 a[8]; i4v v; } H, L;
        #pragma unroll
        for (int j = 0; j < 8; ++j) {
            float v = (j < 4) ? stgA[i][j] : stgB[i][j - 4];
            u16 hh = f2b(v);
            H.a[j] = hh;
            L.a[j] = f2b(v - b2f(hh));
        }
        *(i4v*)&WbH[row * 264 + p16 * 8] = H.v;
        *(i4v*)&WbL[row * 264 + p16 * 8] = L.v;
    }
    __syncthreads();

    const size_t arow = (size_t)(m0 + wave * 16 + lrow) * 1024 + lk8 * 8;
    const u32* hp = hin + arow;

    for (int c = 0; c < 4; ++c) {
        if (c < 3) {
            #pragma unroll
            for (int i = 0; i < 6; ++i) {
                int c16 = i * 256 + tid;
                int row = c16 >> 5, p16 = c16 & 31;
                int grow = (row >> 4) * 1024 + j0 + (row & 15);
                const float* p = Whh + (size_t)grow * 1024 + (c + 1) * 256 + p16 * 8;
                stgA[i] = *(const f4v*)p;
                stgB[i] = *(const f4v*)(p + 4);
            }
        }
        #pragma unroll
        for (int ks = 0; ks < 8; ++ks) {
            int kk = c * 256 + ks * 32;
            int bo = ks * 32 + lk8 * 8;
            u4v w0 = *(const u4v*)(hp + kk);
            u4v w1 = *(const u4v*)(hp + kk + 4);
            s8v ahi, alo;
            unpack8(w0, w1, ahi, alo);
            s8v brh = *(const s8v*)&WbH[(lrow) * 264 + bo];
            s8v brl = *(const s8v*)&WbL[(lrow) * 264 + bo];
            s8v bzh = *(const s8v*)&WbH[(16 + lrow) * 264 + bo];
            s8v bzl = *(const s8v*)&WbL[(16 + lrow) * 264 + bo];
            s8v bnh = *(const s8v*)&WbH[(32 + lrow) * 264 + bo];
            s8v bnl = *(const s8v*)&WbL[(32 + lrow) * 264 + bo];
            acc_r  = mfma16(ahi, brh, acc_r);
            acc_z  = mfma16(ahi, bzh, acc_z);
            acc_hn = mfma16(ahi, bnh, acc_hn);
            acc_r  = mfma16(ahi, brl, acc_r);
            acc_z  = mfma16(ahi, bzl, acc_z);
            acc_hn = mfma16(ahi, bnl, acc_hn);
            acc_r  = mfma16(alo, brh, acc_r);
            acc_z  = mfma16(alo, bzh, acc_z);
            acc_hn = mfma16(alo, bnh, acc_hn);
        }
        __syncthreads();
        if (c < 3) {
            #pragma unroll
            for (int i = 0; i < 6; ++i) {
                int c16 = i * 256 + tid;
                int row = c16 >> 5, p16 = c16 & 31;
                union { u16 a[8]; i4v v; } H, L;
                #pragma unroll
                for (int j = 0; j < 8; ++j) {
                    float v = (j < 4) ? stgA[i][j] : stgB[i][j - 4];
                    u16 hh = f2b(v);
                    H.a[j] = hh;
                    L.a[j] = f2b(v - b2f(hh));
                }
                *(i4v*)&WbH[row * 264 + p16 * 8] = H.v;
                *(i4v*)&WbL[row * 264 + p16 * 8] = L.v;
            }
            __syncthreads();
        }
    }

    const int jcol = j0 + lrow;
    const float bhr = bhh[jcol];
    const float bhz = bhh[1024 + jcol];
    const float bhn = bhh[2048 + jcol];
    #pragma unroll
    for (int reg = 0; reg < 4; ++reg) {
        int brow = m0 + wave * 16 + lk8 * 4 + reg;
        gh_out[(size_t)brow * 3072 + jcol]        = acc_r[reg] + bhr;
        gh_out[(size_t)brow * 3072 + 1024 + jcol] = acc_z[reg] + bhz;
        gh_out[(size_t)brow * 3072 + 2048 + jcol] = acc_hn[reg] + bhn;
    }
}

// ---------------------------------------------------------------------------
// Fused decoder (enc_h packed u32)
__global__ __launch_bounds__(256, 1) void dec_fused(
    const u16* __restrict__ WihH, const u16* __restrict__ WihL,
    const float* __restrict__ bih,
    const float* __restrict__ xdec,
    const u32* __restrict__ e32,
    const float* __restrict__ gh,
    const u16* __restrict__ pWH, const u16* __restrict__ pWL,
    const float* __restrict__ pb,
    float* __restrict__ out)
{
    __shared__ u16 XdH[64 * 72];
    __shared__ u16 XdL[64 * 72];
    __shared__ u16 WiH_[192 * 72];
    __shared__ u16 WiL_[192 * 72];
    __shared__ u16 nsH[64 * 72];
    __shared__ u16 nsL[64 * 72];

    const int tid  = threadIdx.x;
    const int lane = tid & 63;
    const int wave = tid >> 6;
    const int lrow = lane & 15;
    const int lk8  = lane >> 4;
    const int b    = blockIdx.x;

    {
        int row = tid >> 2, q = tid & 3;
        const float* xr = xdec + (size_t)(b * 64 + row) * 63;
        #pragma unroll
        for (int ii = 0; ii < 16; ++ii) {
            int col = q * 16 + ii;
            float v = (col < 63) ? xr[col] : 0.f;
            u16 hh = f2b(v);
            XdH[row * 72 + col] = hh;
            XdL[row * 72 + col] = f2b(v - b2f(hh));
        }
    }

    f4v oacc[4];
    #pragma unroll
    for (int f = 0; f < 4; ++f) oacc[f] = f4v{0.f, 0.f, 0.f, 0.f};

    for (int j0 = 0; j0 < 1024; j0 += 64) {
        #pragma unroll
        for (int k = 0; k < 3; ++k) {
            int c = tid + k * 256;
            int r = c >> 2, qq = c & 3;
            int grow = (r >> 6) * 1024 + j0 + (r & 63);
            const u16* srcH = WihH + (size_t)grow * 64 + qq * 16;
            const u16* srcL = WihL + (size_t)grow * 64 + qq * 16;
            *(i4v*)&WiH_[r * 72 + qq * 16]     = *(const i4v*)srcH;
            *(i4v*)&WiH_[r * 72 + qq * 16 + 8] = *(const i4v*)(srcH + 8);
            *(i4v*)&WiL_[r * 72 + qq * 16]     = *(const i4v*)srcL;
            *(i4v*)&WiL_[r * 72 + qq * 16 + 8] = *(const i4v*)(srcL + 8);
        }
        __syncthreads();

        f4v ar[4], az[4], an[4];
        #pragma unroll
        for (int jf = 0; jf < 4; ++jf) {
            ar[jf] = f4v{0.f, 0.f, 0.f, 0.f};
            az[jf] = f4v{0.f, 0.f, 0.f, 0.f};
            an[jf] = f4v{0.f, 0.f, 0.f, 0.f};
        }
        #pragma unroll
        for (int ks = 0; ks < 2; ++ks) {
            int ao = ks * 32 + lk8 * 8;
            s8v ah = *(const s8v*)&XdH[(wave * 16 + lrow) * 72 + ao];
            s8v al = *(const s8v*)&XdL[(wave * 16 + lrow) * 72 + ao];
            #pragma unroll
            for (int jf = 0; jf < 4; ++jf) {
                s8v brh = *(const s8v*)&WiH_[(jf * 16 + lrow) * 72 + ao];
                s8v brl = *(const s8v*)&WiL_[(jf * 16 + lrow) * 72 + ao];
                s8v bzh = *(const s8v*)&WiH_[(64 + jf * 16 + lrow) * 72 + ao];
                s8v bzl = *(const s8v*)&WiL_[(64 + jf * 16 + lrow) * 72 + ao];
                s8v bnh = *(const s8v*)&WiH_[(128 + jf * 16 + lrow) * 72 + ao];
                s8v bnl = *(const s8v*)&WiL_[(128 + jf * 16 + lrow) * 72 + ao];
                ar[jf] = mfma16(ah, brh, ar[jf]);
                az[jf] = mfma16(ah, bzh, az[jf]);
                an[jf] = mfma16(ah, bnh, an[jf]);
                ar[jf] = mfma16(ah, brl, ar[jf]);
                az[jf] = mfma16(ah, bzl, az[jf]);
                an[jf] = mfma16(ah, bnl, an[jf]);
                ar[jf] = mfma16(al, brh, ar[jf]);
                az[jf] = mfma16(al, bzh, az[jf]);
                an[jf] = mfma16(al, bnh, an[jf]);
            }
        }

        #pragma unroll
        for (int jf = 0; jf < 4; ++jf) {
            int j = j0 + jf * 16 + lrow;
            float ghr = gh[(size_t)b * 3072 + j];
            float ghz = gh[(size_t)b * 3072 + 1024 + j];
            float ghn = gh[(size_t)b * 3072 + 2048 + j];
            float bir = bih[j];
            float biz = bih[1024 + j];
            float bin = bih[2048 + j];
            u32 pk = e32[(size_t)b * 1024 + j];
            float he = b2f((u16)(pk & 0xffffu)) + b2f((u16)(pk >> 16));
            #pragma unroll
            for (int reg = 0; reg < 4; ++reg) {
                float r  = sigf(ar[jf][reg] + bir + ghr);
                float z  = sigf(az[jf][reg] + biz + ghz);
                float nn = tanhf(an[jf][reg] + bin + r * ghn);
                float v  = (1.f - z) * nn + z * he;
                u16 hh = f2b(v);
                int lo_i = (wave * 16 + lk8 * 4 + reg) * 72 + jf * 16 + lrow;
                nsH[lo_i] = hh;
                nsL[lo_i] = f2b(v - b2f(hh));
            }
        }
        __syncthreads();

        #pragma unroll
        for (int ks = 0; ks < 2; ++ks) {
            int ao = ks * 32 + lk8 * 8;
            s8v ah = *(const s8v*)&nsH[(wave * 16 + lrow) * 72 + ao];
            s8v al = *(const s8v*)&nsL[(wave * 16 + lrow) * 72 + ao];
            #pragma unroll
            for (int f = 0; f < 4; ++f) {
                size_t bo = (size_t)(f * 16 + lrow) * 1024 + j0 + ks * 32 + lk8 * 8;
                s8v bh = *(const s8v*)(pWH + bo);
                s8v bl = *(const s8v*)(pWL + bo);
                oacc[f] = mfma16(ah, bh, oacc[f]);
                oacc[f] = mfma16(ah, bl, oacc[f]);
                oacc[f] = mfma16(al, bh, oacc[f]);
            }
        }
        __syncthreads();
    }

    #pragma unroll
    for (int f = 0; f < 4; ++f) {
        int o = f * 16 + lrow;
        if (o < 63) {
            float pbv = pb[o];
            #pragma unroll
            for (int reg = 0; reg < 4; ++reg) {
                int t = wave * 16 + lk8 * 4 + reg;
                out[((size_t)(b * 64 + t)) * 63 + o] = oacc[f][reg] + pbv;
            }
        }
    }
}

// ---------------------------------------------------------------------------
extern "C" void kernel_launch(void* const* d_in, const int* in_sizes, int n_in,
                              void* d_out, int out_size, void* d_ws, size_t ws_size,
                              hipStream_t stream)
{
    const float* enc_x = (const float*)d_in[0];
    const float* dec_x = (const float*)d_in[1];
    const float* eWih  = (const float*)d_in[2];
    const float* eWhh  = (const float*)d_in[3];
    const float* ebih  = (const float*)d_in[4];
    const float* ebhh  = (const float*)d_in[5];
    const float* dWih  = (const float*)d_in[6];
    const float* dWhh  = (const float*)d_in[7];
    const float* dbih  = (const float*)d_in[8];
    const float* dbhh  = (const float*)d_in[9];
    const float* pW    = (const float*)d_in[10];
    const float* pb    = (const float*)d_in[11];

    char* ws = (char*)d_ws;

    // layout: 129MB hbuf(packed) + 16KB ep + 3MB ghd + 4x384KB Wih + 2x128KB pW
    u32*   hbuf  = (u32*)(ws);                     // 129 x 1MB rotating packed h
    int*   ep    = (int*)(ws + 135266304);         // 16 KB sub-counters
    float* ghd   = (float*)(ws + 135282688);       // 3 MB
    u16*   eWihH = (u16*)(ws + 138428416);         // 384 KB each
    u16*   eWihL = (u16*)(ws + 138821632);
    u16*   dWihH = (u16*)(ws + 139214848);
    u16*   dWihL = (u16*)(ws + 139608064);
    u16*   pWH   = (u16*)(ws + 140001280);         // 128 KB each
    u16*   pWL   = (u16*)(ws + 140132352);

    // fused prologue: Wih/pW pad-splits + zero hbuf[0] + zero counters
    prologue<<<dim3(2049), dim3(256), 0, stream>>>(
        eWih, dWih, pW, eWihH, eWihL, dWihH, dWihL, pWH, pWL,
        (i4v*)hbuf, (i4v*)ep);

    // persistent encoder: all 128 steps, one launch
    enc_persist13<<<dim3(256), dim3(512), 0, stream>>>(
        eWhh, eWihH, eWihL, ebih, ebhh, enc_x, hbuf, ep);

    u32* Hfin = hbuf + (size_t)128 * 262144;       // buf[128]

    // gh_dec = enc_h @ dec_Whh^T + dec_bhh (dWhh split on the fly)
    gru_gemm1<<<dim3(256), dim3(256), 0, stream>>>(dWhh, dbhh, Hfin, ghd);

    // fused decoder gates + projection -> fp32 out
    dec_fused<<<dim3(256), dim3(256), 0, stream>>>(
        dWihH, dWihL, dbih, dec_x, Hfin, ghd, pWH, pWL, pb, (float*)d_out);
}

// Round 9
// 1482.022 us; speedup vs baseline: 1.2431x; 1.0498x over previous
//
#include <hip/hip_runtime.h>

// Seq2Seq GRU: B=256, S=128, T=64, I=63, H=1024. Inputs fp32, output fp32.
// All GEMMs: bf16 hi+lo 3-term split emulation (~fp32 accuracy).
// Encoder v14 = R3's enc_persist8 VERBATIM (measured session-best encoder:
//   1374us) + R8's fused prologue (measured -60us non-enc savings).
//   R8's early-post experiment REVERTED: 32 RMWs/line/step (4x hot-line
//   contention) + slowest-of-32 wait regressed enc by ~100us. R3's
//   barrier-then-one-post is the measured optimum of 8 protocol variants
//   tried this session (R1 counter+fence-free, R3 per-wave waits, R4
//   dual-interleave, R5 data-as-flag, R7 XCD-pair locality, R8 early-post).

typedef unsigned short u16;
typedef unsigned int   u32;
typedef __attribute__((ext_vector_type(8))) short s8v;   // 8 x bf16 (4 VGPRs)
typedef __attribute__((ext_vector_type(4))) float f4v;   // MFMA acc
typedef __attribute__((ext_vector_type(4))) int  i4v;    // 16B copy unit
typedef __attribute__((ext_vector_type(4))) unsigned int u4v;

__device__ __forceinline__ float b2f(u16 u) {
    return __uint_as_float(((u32)u) << 16);
}
__device__ __forceinline__ u16 f2b(float f) {   // round-to-nearest-even
    u32 x = __float_as_uint(f);
    u32 r = x + 0x7fffu + ((x >> 16) & 1u);
    return (u16)(r >> 16);
}
__device__ __forceinline__ float sigf(float x) {
    return 1.0f / (1.0f + __expf(-x));
}
__device__ __forceinline__ f4v mfma16(s8v a, s8v b, f4v c) {
    return __builtin_amdgcn_mfma_f32_16x16x32_bf16(a, b, c, 0, 0, 0);
}
// 8 packed u32 (hh|ll<<16) -> hi-plane s8v + lo-plane s8v
__device__ __forceinline__ void unpack8(u4v w0, u4v w1, s8v& hi, s8v& lo) {
    u32 c0 = w0[0], c1 = w0[1], c2 = w0[2], c3 = w0[3];
    u32 c4 = w1[0], c5 = w1[1], c6 = w1[2], c7 = w1[3];
    union { u32 u[4]; s8v v; } H, L;
    H.u[0] = (c0 & 0xffffu) | (c1 << 16);
    H.u[1] = (c2 & 0xffffu) | (c3 << 16);
    H.u[2] = (c4 & 0xffffu) | (c5 << 16);
    H.u[3] = (c6 & 0xffffu) | (c7 << 16);
    L.u[0] = (c0 >> 16) | (c1 & 0xffff0000u);
    L.u[1] = (c2 >> 16) | (c3 & 0xffff0000u);
    L.u[2] = (c4 >> 16) | (c5 & 0xffff0000u);
    L.u[3] = (c6 >> 16) | (c7 & 0xffff0000u);
    hi = H.v; lo = L.v;
}

// ---------------------------------------------------------------------------
// Fused prologue (R8-proven): blocks [0,768) eWih pad-split, [768,1536)
// dWih pad-split, [1536,1792) pW pad-split, [1792,2048) zero hbuf[0],
// [2048] zero counters.
__global__ __launch_bounds__(256) void prologue(
    const float* __restrict__ eWih, const float* __restrict__ dWih,
    const float* __restrict__ pW,
    u16* __restrict__ eWihH, u16* __restrict__ eWihL,
    u16* __restrict__ dWihH, u16* __restrict__ dWihL,
    u16* __restrict__ pWH, u16* __restrict__ pWL,
    i4v* __restrict__ hbuf0, i4v* __restrict__ ep)
{
    const int b = blockIdx.x;
    const int tid = threadIdx.x;
    if (b < 1536) {
        // Wih (3072 x 63 fp32) -> padded (3072 x 64) hi+lo, col 63 = 0
        const float* src = (b < 768) ? eWih : dWih;
        u16* hi = (b < 768) ? eWihH : dWihH;
        u16* lo = (b < 768) ? eWihL : dWihL;
        int idx = ((b < 768) ? b : b - 768) * 256 + tid;
        int row = idx >> 6, col = idx & 63;
        float v = (col < 63) ? src[(size_t)row * 63 + col] : 0.f;
        u16 h = f2b(v);
        hi[idx] = h;
        lo[idx] = f2b(v - b2f(h));
    } else if (b < 1792) {
        // proj_W (63 x 1024 fp32) -> padded (64 x 1024) hi+lo, row 63 = 0
        int idx = (b - 1536) * 256 + tid;
        float v = (idx < 63 * 1024) ? pW[idx] : 0.f;
        u16 h = f2b(v);
        pWH[idx] = h;
        pWL[idx] = f2b(v - b2f(h));
    } else if (b < 2048) {
        // zero hbuf[0]: 65536 i4v
        i4v z = {0, 0, 0, 0};
        hbuf0[(b - 1792) * 256 + tid] = z;
    } else {
        // zero counters: 1024 i4v
        i4v z = {0, 0, 0, 0};
        for (int i = tid; i < 1024; i += 256) ep[i] = z;
    }
}

// ---------------------------------------------------------------------------
// Persistent encoder v14 == R3's enc_persist8 (verbatim body).
__global__ __launch_bounds__(512, 1) void enc_persist14(
    const float* __restrict__ Whh,                 // fp32 3072 x 1024
    const u16* __restrict__ WihH, const u16* __restrict__ WihL,
    const float* __restrict__ bih, const float* __restrict__ bhh,
    const float* __restrict__ xenc,
    u32* __restrict__ hbuf,                        // 129 x (256x1024) packed
    int* __restrict__ ep)                          // 32 sub-counters x 64B
{
    __shared__ f4v red[8][4][3][64];   // 98.3 KB: per-wave k-slice partials
    __shared__ u16 WisH[48 * 72];      // Wih slice (persistent)
    __shared__ u16 WisL[48 * 72];

    // one-time: drop stale lines from a previous graph replay
    __builtin_amdgcn_fence(__ATOMIC_ACQUIRE, "agent");

    const int tid  = threadIdx.x;
    const int lane = tid & 63;
    const int wave = tid >> 6;          // 0..7 : k-slice owner, k0 = wave*128
    const int lrow = lane & 15;
    const int lk8  = lane >> 4;
    // XCD-aware swizzle: bid&7 = XCD; XCD owns a 128-col j-range.
    const int bid = blockIdx.x;
    const int xcd = bid & 7;
    const int y   = bid >> 3;
    const int mt  = y & 3;
    const int jt  = xcd * 8 + (y >> 2);
    const int m0 = mt * 64;
    const int j0 = jt * 16;

    // sub-counter (mt, xcd): incremented by its 8 blocks each step.
    int* subCtr  = ep + (mt * 8 + xcd) * 16;
    // wave w's producers (jt' in [8w,8w+8)) all live on XCD w -> ONE counter.
    int* waveCtr = ep + (mt * 8 + wave) * 16;

    // ---- one-time: Wih slice into LDS
    if (tid < 192) {
        int wr = tid >> 2, qq = tid & 3;
        int grow = (wr >> 4) * 1024 + j0 + (wr & 15);
        const u16* wpH = WihH + (size_t)grow * 64 + qq * 16;
        const u16* wpL = WihL + (size_t)grow * 64 + qq * 16;
        *(i4v*)&WisH[wr * 72 + qq * 16]     = *(const i4v*)wpH;
        *(i4v*)&WisH[wr * 72 + qq * 16 + 8] = *(const i4v*)(wpH + 8);
        *(i4v*)&WisL[wr * 72 + qq * 16]     = *(const i4v*)wpL;
        *(i4v*)&WisL[wr * 72 + qq * 16 + 8] = *(const i4v*)(wpL + 8);
    }

    // ---- one-time: this wave's Whh K-slice fp32 -> bf16 hi+lo in registers
    s8v bHf[3][4], bLf[3][4];
    const int k0 = wave * 128;
    #pragma unroll
    for (int gg = 0; gg < 3; ++gg)
        #pragma unroll
        for (int ks = 0; ks < 4; ++ks) {
            const float* p = Whh + (size_t)(gg * 1024 + j0 + lrow) * 1024 +
                             k0 + ks * 32 + lk8 * 8;
            f4v a = *(const f4v*)p;
            f4v b = *(const f4v*)(p + 4);
            union { u16 a[8]; s8v v; } H, L;
            #pragma unroll
            for (int j = 0; j < 8; ++j) {
                float v = (j < 4) ? a[j] : b[j - 4];
                u16 hh = f2b(v);
                H.a[j] = hh;
                L.a[j] = f2b(v - b2f(hh));
            }
            bHf[gg][ks] = H.v;
            bLf[gg][ks] = L.v;
        }

    const int jcol = j0 + lrow;
    const float bhr = bhh[jcol], bhz = bhh[1024 + jcol], bhn = bhh[2048 + jcol];
    const float bir = bih[jcol], biz = bih[1024 + jcol], bin = bih[2048 + jcol];

    // A-load element offsets per m-tile (u32 elements)
    size_t aoff[4];
    #pragma unroll
    for (int mtile = 0; mtile < 4; ++mtile)
        aoff[mtile] = (size_t)(m0 + mtile * 16 + lrow) * 1024 + k0 + lk8 * 8;

    // gi / epilogue waves: wave v (0..3) owns m-tile v
    const float* xrow = xenc + (size_t)(m0 + (wave & 3) * 16 + lrow) * 8064;
    float hprev[4] = {0.f, 0.f, 0.f, 0.f};

    float xf[16];
    if (wave < 4) {
        #pragma unroll
        for (int ks = 0; ks < 2; ++ks)
            #pragma unroll
            for (int j = 0; j < 8; ++j) {
                int col = ks * 32 + lk8 * 8 + j;
                xf[ks * 8 + j] = (col < 63) ? xrow[col] : 0.f;
            }
    }

    __syncthreads();   // Wis ready

    for (int s = 0; s < 128; ++s) {
        const u32* hin = hbuf + (size_t)s * 262144;        // read buf[s]
        u32* hout      = hbuf + (size_t)(s + 1) * 262144;  // write buf[s+1]

        // ---- gi (waves 0-3): h-independent -> compute in the wait shadow
        f4v gi_r = {0.f, 0.f, 0.f, 0.f};
        f4v gi_z = {0.f, 0.f, 0.f, 0.f};
        f4v gi_n = {0.f, 0.f, 0.f, 0.f};
        if (wave < 4) {
            #pragma unroll
            for (int ks = 0; ks < 2; ++ks) {
                union { u16 a[8]; s8v v; } xh, xl;
                #pragma unroll
                for (int j = 0; j < 8; ++j) {
                    float v = xf[ks * 8 + j];
                    u16 hh = f2b(v);
                    xh.a[j] = hh;
                    xl.a[j] = f2b(v - b2f(hh));
                }
                int ao = ks * 32 + lk8 * 8;
                s8v brh = *(const s8v*)&WisH[(lrow) * 72 + ao];
                s8v brl = *(const s8v*)&WisL[(lrow) * 72 + ao];
                s8v bzh = *(const s8v*)&WisH[(16 + lrow) * 72 + ao];
                s8v bzl = *(const s8v*)&WisL[(16 + lrow) * 72 + ao];
                s8v bnh = *(const s8v*)&WisH[(32 + lrow) * 72 + ao];
                s8v bnl = *(const s8v*)&WisL[(32 + lrow) * 72 + ao];
                gi_r = mfma16(xh.v, brh, gi_r);
                gi_z = mfma16(xh.v, bzh, gi_z);
                gi_n = mfma16(xh.v, bnh, gi_n);
                gi_r = mfma16(xh.v, brl, gi_r);
                gi_z = mfma16(xh.v, bzl, gi_z);
                gi_n = mfma16(xh.v, bnl, gi_n);
                gi_r = mfma16(xl.v, brh, gi_r);
                gi_z = mfma16(xl.v, bzh, gi_z);
                gi_n = mfma16(xl.v, bnh, gi_n);
            }
        }

        // ---- per-wave wait: only THIS wave's 8 producers (one counter).
        if (s) {
            const int tgt = s * 8;
            while (__hip_atomic_load(waveCtr, __ATOMIC_RELAXED,
                                     __HIP_MEMORY_SCOPE_SYSTEM) < tgt)
                __builtin_amdgcn_s_sleep(1);
        }

        // ---- K loop: 4 m-tiles x 4 ks, B in regs, packed-A unpack
        f4v accr[4], accz[4], acchn[4];
        #pragma unroll
        for (int m = 0; m < 4; ++m) {
            accr[m]  = f4v{0.f, 0.f, 0.f, 0.f};
            accz[m]  = f4v{0.f, 0.f, 0.f, 0.f};
            acchn[m] = f4v{0.f, 0.f, 0.f, 0.f};
        }
        #pragma unroll
        for (int mtile = 0; mtile < 4; ++mtile) {
            #pragma unroll
            for (int ks = 0; ks < 4; ++ks) {
                const u32* p = hin + aoff[mtile] + ks * 32;
                u4v w0 = *(const u4v*)p;
                u4v w1 = *(const u4v*)(p + 4);
                s8v ahi, alo;
                unpack8(w0, w1, ahi, alo);
                accr[mtile]  = mfma16(ahi, bHf[0][ks], accr[mtile]);
                accz[mtile]  = mfma16(ahi, bHf[1][ks], accz[mtile]);
                acchn[mtile] = mfma16(ahi, bHf[2][ks], acchn[mtile]);
                accr[mtile]  = mfma16(ahi, bLf[0][ks], accr[mtile]);
                accz[mtile]  = mfma16(ahi, bLf[1][ks], accz[mtile]);
                acchn[mtile] = mfma16(ahi, bLf[2][ks], acchn[mtile]);
                accr[mtile]  = mfma16(alo, bHf[0][ks], accr[mtile]);
                accz[mtile]  = mfma16(alo, bHf[1][ks], accz[mtile]);
                acchn[mtile] = mfma16(alo, bHf[2][ks], acchn[mtile]);
            }
        }

        // ---- write k-slice partials
        #pragma unroll
        for (int m = 0; m < 4; ++m) {
            red[wave][m][0][lane] = accr[m];
            red[wave][m][1][lane] = accz[m];
            red[wave][m][2][lane] = acchn[m];
        }
        __syncthreads();

        // ---- epilogue (waves 0-3): 8-way reduce, gates, packed h store
        if (wave < 4) {
            f4v sr = {0.f, 0.f, 0.f, 0.f};
            f4v sz = {0.f, 0.f, 0.f, 0.f};
            f4v sh = {0.f, 0.f, 0.f, 0.f};
            #pragma unroll
            for (int w = 0; w < 8; ++w) {
                sr += red[w][wave][0][lane];
                sz += red[w][wave][1][lane];
                sh += red[w][wave][2][lane];
            }
            #pragma unroll
            for (int reg = 0; reg < 4; ++reg) {
                int brow = m0 + wave * 16 + lk8 * 4 + reg;
                float rr = sigf(sr[reg] + gi_r[reg] + bir + bhr);
                float zz = sigf(sz[reg] + gi_z[reg] + biz + bhz);
                float nn = tanhf(gi_n[reg] + bin + rr * (sh[reg] + bhn));
                float h = (1.f - zz) * nn + zz * hprev[reg];
                u16 hh = f2b(h);
                u16 ll = f2b(h - b2f(hh));
                hprev[reg] = b2f(hh) + b2f(ll);
                u32 pk = (u32)hh | ((u32)ll << 16);
                // write-through (sc0 sc1): visible once vmcnt drains at the
                // barrier below -> no wbl2 needed.
                __hip_atomic_store(&hout[(size_t)brow * 1024 + jcol], pk,
                                   __ATOMIC_RELAXED, __HIP_MEMORY_SCOPE_SYSTEM);
            }
        }

        __syncthreads();   // drains h stores (vmcnt 0 per wave)
        if (tid == 0)
            __hip_atomic_fetch_add(subCtr, 1, __ATOMIC_RELAXED,
                                   __HIP_MEMORY_SCOPE_SYSTEM);
        // prefetch next step's x (immutable input)
        if (wave < 4) {
            int sn = (s < 127) ? s + 1 : 127;
            const float* xr = xrow + sn * 63;
            #pragma unroll
            for (int ks = 0; ks < 2; ++ks)
                #pragma unroll
                for (int j = 0; j < 8; ++j) {
                    int col = ks * 32 + lk8 * 8 + j;
                    xf[ks * 8 + j] = (col < 63) ? xr[col] : 0.f;
                }
        }
    }
}

// ---------------------------------------------------------------------------
// gh_dec = enc_h @ dec_Whh^T + dec_bhh (fp32 out). dWhh split on the fly.
__global__ __launch_bounds__(256, 1) void gru_gemm1(
    const float* __restrict__ Whh,                 // fp32 3072 x 1024
    const float* __restrict__ bhh,
    const u32* __restrict__ hin,                   // packed hh|ll<<16
    float* __restrict__ gh_out)
{
    __shared__ u16 WbH[48 * 264];
    __shared__ u16 WbL[48 * 264];

    const int tid  = threadIdx.x;
    const int lane = tid & 63;
    const int wave = tid >> 6;
    const int lrow = lane & 15;
    const int lk8  = lane >> 4;
    const int mt = blockIdx.x & 3;
    const int jt = blockIdx.x >> 2;
    const int m0 = mt * 64;
    const int j0 = jt * 16;

    f4v acc_r  = {0.f, 0.f, 0.f, 0.f};
    f4v acc_z  = {0.f, 0.f, 0.f, 0.f};
    f4v acc_hn = {0.f, 0.f, 0.f, 0.f};

    f4v stgA[6], stgB[6];
    #pragma unroll
    for (int i = 0; i < 6; ++i) {
        int c16 = i * 256 + tid;
        int row = c16 >> 5, p16 = c16 & 31;
        int grow = (row >> 4) * 1024 + j0 + (row & 15);
        const float* p = Whh + (size_t)grow * 1024 + p16 * 8;
        stgA[i] = *(const f4v*)p;
        stgB[i] = *(const f4v*)(p + 4);
    }
    #pragma unroll
    for (int i = 0; i < 6; ++i) {
        int c16 = i * 256 + tid;
        int row = c16 >> 5, p16 = c16 & 31;
        union { u16 a[8]; i4v v; } H, L;
        #pragma unroll
        for (int j = 0; j < 8; ++j) {
            float v = (j < 4) ? stgA[i][j] : stgB[i][j - 4];
            u16 hh = f2b(v);
            H.a[j] = hh;
            L.a[j] = f2b(v - b2f(hh));
        }
        *(i4v*)&WbH[row * 264 + p16 * 8] = H.v;
        *(i4v*)&WbL[row * 264 + p16 * 8] = L.v;
    }
    __syncthreads();

    const size_t arow = (size_t)(m0 + wave * 16 + lrow) * 1024 + lk8 * 8;
    const u32* hp = hin + arow;

    for (int c = 0; c < 4; ++c) {
        if (c < 3) {
            #pragma unroll
            for (int i = 0; i < 6; ++i) {
                int c16 = i * 256 + tid;
                int row = c16 >> 5, p16 = c16 & 31;
                int grow = (row >> 4) * 1024 + j0 + (row & 15);
                const float* p = Whh + (size_t)grow * 1024 + (c + 1) * 256 + p16 * 8;
                stgA[i] = *(const f4v*)p;
                stgB[i] = *(const f4v*)(p + 4);
            }
        }
        #pragma unroll
        for (int ks = 0; ks < 8; ++ks) {
            int kk = c * 256 + ks * 32;
            int bo = ks * 32 + lk8 * 8;
            u4v w0 = *(const u4v*)(hp + kk);
            u4v w1 = *(const u4v*)(hp + kk + 4);
            s8v ahi, alo;
            unpack8(w0, w1, ahi, alo);
            s8v brh = *(const s8v*)&WbH[(lrow) * 264 + bo];
            s8v brl = *(const s8v*)&WbL[(lrow) * 264 + bo];
            s8v bzh = *(const s8v*)&WbH[(16 + lrow) * 264 + bo];
            s8v bzl = *(const s8v*)&WbL[(16 + lrow) * 264 + bo];
            s8v bnh = *(const s8v*)&WbH[(32 + lrow) * 264 + bo];
            s8v bnl = *(const s8v*)&WbL[(32 + lrow) * 264 + bo];
            acc_r  = mfma16(ahi, brh, acc_r);
            acc_z  = mfma16(ahi, bzh, acc_z);
            acc_hn = mfma16(ahi, bnh, acc_hn);
            acc_r  = mfma16(ahi, brl, acc_r);
            acc_z  = mfma16(ahi, bzl, acc_z);
            acc_hn = mfma16(ahi, bnl, acc_hn);
            acc_r  = mfma16(alo, brh, acc_r);
            acc_z  = mfma16(alo, bzh, acc_z);
            acc_hn = mfma16(alo, bnh, acc_hn);
        }
        __syncthreads();
        if (c < 3) {
            #pragma unroll
            for (int i = 0; i < 6; ++i) {
                int c16 = i * 256 + tid;
                int row = c16 >> 5, p16 = c16 & 31;
                union { u16 a[8]; i4v v; } H, L;
                #pragma unroll
                for (int j = 0; j < 8; ++j) {
                    float v = (j < 4) ? stgA[i][j] : stgB[i][j - 4];
                    u16 hh = f2b(v);
                    H.a[j] = hh;
                    L.a[j] = f2b(v - b2f(hh));
                }
                *(i4v*)&WbH[row * 264 + p16 * 8] = H.v;
                *(i4v*)&WbL[row * 264 + p16 * 8] = L.v;
            }
            __syncthreads();
        }
    }

    const int jcol = j0 + lrow;
    const float bhr = bhh[jcol];
    const float bhz = bhh[1024 + jcol];
    const float bhn = bhh[2048 + jcol];
    #pragma unroll
    for (int reg = 0; reg < 4; ++reg) {
        int brow = m0 + wave * 16 + lk8 * 4 + reg;
        gh_out[(size_t)brow * 3072 + jcol]        = acc_r[reg] + bhr;
        gh_out[(size_t)brow * 3072 + 1024 + jcol] = acc_z[reg] + bhz;
        gh_out[(size_t)brow * 3072 + 2048 + jcol] = acc_hn[reg] + bhn;
    }
}

// ---------------------------------------------------------------------------
// Fused decoder (enc_h packed u32)
__global__ __launch_bounds__(256, 1) void dec_fused(
    const u16* __restrict__ WihH, const u16* __restrict__ WihL,
    const float* __restrict__ bih,
    const float* __restrict__ xdec,
    const u32* __restrict__ e32,
    const float* __restrict__ gh,
    const u16* __restrict__ pWH, const u16* __restrict__ pWL,
    const float* __restrict__ pb,
    float* __restrict__ out)
{
    __shared__ u16 XdH[64 * 72];
    __shared__ u16 XdL[64 * 72];
    __shared__ u16 WiH_[192 * 72];
    __shared__ u16 WiL_[192 * 72];
    __shared__ u16 nsH[64 * 72];
    __shared__ u16 nsL[64 * 72];

    const int tid  = threadIdx.x;
    const int lane = tid & 63;
    const int wave = tid >> 6;
    const int lrow = lane & 15;
    const int lk8  = lane >> 4;
    const int b    = blockIdx.x;

    {
        int row = tid >> 2, q = tid & 3;
        const float* xr = xdec + (size_t)(b * 64 + row) * 63;
        #pragma unroll
        for (int ii = 0; ii < 16; ++ii) {
            int col = q * 16 + ii;
            float v = (col < 63) ? xr[col] : 0.f;
            u16 hh = f2b(v);
            XdH[row * 72 + col] = hh;
            XdL[row * 72 + col] = f2b(v - b2f(hh));
        }
    }

    f4v oacc[4];
    #pragma unroll
    for (int f = 0; f < 4; ++f) oacc[f] = f4v{0.f, 0.f, 0.f, 0.f};

    for (int j0 = 0; j0 < 1024; j0 += 64) {
        #pragma unroll
        for (int k = 0; k < 3; ++k) {
            int c = tid + k * 256;
            int r = c >> 2, qq = c & 3;
            int grow = (r >> 6) * 1024 + j0 + (r & 63);
            const u16* srcH = WihH + (size_t)grow * 64 + qq * 16;
            const u16* srcL = WihL + (size_t)grow * 64 + qq * 16;
            *(i4v*)&WiH_[r * 72 + qq * 16]     = *(const i4v*)srcH;
            *(i4v*)&WiH_[r * 72 + qq * 16 + 8] = *(const i4v*)(srcH + 8);
            *(i4v*)&WiL_[r * 72 + qq * 16]     = *(const i4v*)srcL;
            *(i4v*)&WiL_[r * 72 + qq * 16 + 8] = *(const i4v*)(srcL + 8);
        }
        __syncthreads();

        f4v ar[4], az[4], an[4];
        #pragma unroll
        for (int jf = 0; jf < 4; ++jf) {
            ar[jf] = f4v{0.f, 0.f, 0.f, 0.f};
            az[jf] = f4v{0.f, 0.f, 0.f, 0.f};
            an[jf] = f4v{0.f, 0.f, 0.f, 0.f};
        }
        #pragma unroll
        for (int ks = 0; ks < 2; ++ks) {
            int ao = ks * 32 + lk8 * 8;
            s8v ah = *(const s8v*)&XdH[(wave * 16 + lrow) * 72 + ao];
            s8v al = *(const s8v*)&XdL[(wave * 16 + lrow) * 72 + ao];
            #pragma unroll
            for (int jf = 0; jf < 4; ++jf) {
                s8v brh = *(const s8v*)&WiH_[(jf * 16 + lrow) * 72 + ao];
                s8v brl = *(const s8v*)&WiL_[(jf * 16 + lrow) * 72 + ao];
                s8v bzh = *(const s8v*)&WiH_[(64 + jf * 16 + lrow) * 72 + ao];
                s8v bzl = *(const s8v*)&WiL_[(64 + jf * 16 + lrow) * 72 + ao];
                s8v bnh = *(const s8v*)&WiH_[(128 + jf * 16 + lrow) * 72 + ao];
                s8v bnl = *(const s8v*)&WiL_[(128 + jf * 16 + lrow) * 72 + ao];
                ar[jf] = mfma16(ah, brh, ar[jf]);
                az[jf] = mfma16(ah, bzh, az[jf]);
                an[jf] = mfma16(ah, bnh, an[jf]);
                ar[jf] = mfma16(ah, brl, ar[jf]);
                az[jf] = mfma16(ah, bzl, az[jf]);
                an[jf] = mfma16(ah, bnl, an[jf]);
                ar[jf] = mfma16(al, brh, ar[jf]);
                az[jf] = mfma16(al, bzh, az[jf]);
                an[jf] = mfma16(al, bnh, an[jf]);
            }
        }

        #pragma unroll
        for (int jf = 0; jf < 4; ++jf) {
            int j = j0 + jf * 16 + lrow;
            float ghr = gh[(size_t)b * 3072 + j];
            float ghz = gh[(size_t)b * 3072 + 1024 + j];
            float ghn = gh[(size_t)b * 3072 + 2048 + j];
            float bir = bih[j];
            float biz = bih[1024 + j];
            float bin = bih[2048 + j];
            u32 pk = e32[(size_t)b * 1024 + j];
            float he = b2f((u16)(pk & 0xffffu)) + b2f((u16)(pk >> 16));
            #pragma unroll
            for (int reg = 0; reg < 4; ++reg) {
                float r  = sigf(ar[jf][reg] + bir + ghr);
                float z  = sigf(az[jf][reg] + biz + ghz);
                float nn = tanhf(an[jf][reg] + bin + r * ghn);
                float v  = (1.f - z) * nn + z * he;
                u16 hh = f2b(v);
                int lo_i = (wave * 16 + lk8 * 4 + reg) * 72 + jf * 16 + lrow;
                nsH[lo_i] = hh;
                nsL[lo_i] = f2b(v - b2f(hh));
            }
        }
        __syncthreads();

        #pragma unroll
        for (int ks = 0; ks < 2; ++ks) {
            int ao = ks * 32 + lk8 * 8;
            s8v ah = *(const s8v*)&nsH[(wave * 16 + lrow) * 72 + ao];
            s8v al = *(const s8v*)&nsL[(wave * 16 + lrow) * 72 + ao];
            #pragma unroll
            for (int f = 0; f < 4; ++f) {
                size_t bo = (size_t)(f * 16 + lrow) * 1024 + j0 + ks * 32 + lk8 * 8;
                s8v bh = *(const s8v*)(pWH + bo);
                s8v bl = *(const s8v*)(pWL + bo);
                oacc[f] = mfma16(ah, bh, oacc[f]);
                oacc[f] = mfma16(ah, bl, oacc[f]);
                oacc[f] = mfma16(al, bh, oacc[f]);
            }
        }
        __syncthreads();
    }

    #pragma unroll
    for (int f = 0; f < 4; ++f) {
        int o = f * 16 + lrow;
        if (o < 63) {
            float pbv = pb[o];
            #pragma unroll
            for (int reg = 0; reg < 4; ++reg) {
                int t = wave * 16 + lk8 * 4 + reg;
                out[((size_t)(b * 64 + t)) * 63 + o] = oacc[f][reg] + pbv;
            }
        }
    }
}

// ---------------------------------------------------------------------------
extern "C" void kernel_launch(void* const* d_in, const int* in_sizes, int n_in,
                              void* d_out, int out_size, void* d_ws, size_t ws_size,
                              hipStream_t stream)
{
    const float* enc_x = (const float*)d_in[0];
    const float* dec_x = (const float*)d_in[1];
    const float* eWih  = (const float*)d_in[2];
    const float* eWhh  = (const float*)d_in[3];
    const float* ebih  = (const float*)d_in[4];
    const float* ebhh  = (const float*)d_in[5];
    const float* dWih  = (const float*)d_in[6];
    const float* dWhh  = (const float*)d_in[7];
    const float* dbih  = (const float*)d_in[8];
    const float* dbhh  = (const float*)d_in[9];
    const float* pW    = (const float*)d_in[10];
    const float* pb    = (const float*)d_in[11];

    char* ws = (char*)d_ws;

    // layout: 129MB hbuf(packed) + 16KB ep + 3MB ghd + 4x384KB Wih + 2x128KB pW
    u32*   hbuf  = (u32*)(ws);                     // 129 x 1MB rotating packed h
    int*   ep    = (int*)(ws + 135266304);         // 16 KB sub-counters
    float* ghd   = (float*)(ws + 135282688);       // 3 MB
    u16*   eWihH = (u16*)(ws + 138428416);         // 384 KB each
    u16*   eWihL = (u16*)(ws + 138821632);
    u16*   dWihH = (u16*)(ws + 139214848);
    u16*   dWihL = (u16*)(ws + 139608064);
    u16*   pWH   = (u16*)(ws + 140001280);         // 128 KB each
    u16*   pWL   = (u16*)(ws + 140132352);

    // fused prologue: Wih/pW pad-splits + zero hbuf[0] + zero counters
    prologue<<<dim3(2049), dim3(256), 0, stream>>>(
        eWih, dWih, pW, eWihH, eWihL, dWihH, dWihL, pWH, pWL,
        (i4v*)hbuf, (i4v*)ep);

    // persistent encoder: all 128 steps, one launch
    enc_persist14<<<dim3(256), dim3(512), 0, stream>>>(
        eWhh, eWihH, eWihL, ebih, ebhh, enc_x, hbuf, ep);

    u32* Hfin = hbuf + (size_t)128 * 262144;       // buf[128]

    // gh_dec = enc_h @ dec_Whh^T + dec_bhh (dWhh split on the fly)
    gru_gemm1<<<dim3(256), dim3(256), 0, stream>>>(dWhh, dbhh, Hfin, ghd);

    // fused decoder gates + projection -> fp32 out
    dec_fused<<<dim3(256), dim3(256), 0, stream>>>(
        dWihH, dWihL, dbih, dec_x, Hfin, ghd, pWH, pWL, pb, (float*)d_out);
}